// Round 3
// baseline (313.791 us; speedup 1.0000x reference)
//
#include <hip/hip_runtime.h>

// PadWithin: out[b,c,2i,2j] = feats[b,c,i,j], all other entries zero.
// feats: (16,64,128,128) fp32 -> out: (16,64,256,256) fp32.
//
// Two-dispatch split (discriminating experiment, round 3):
//   A) zero_kernel: zero the entire 268 MB output. Pure f4 store stream,
//      the exact shape of __amd_rocclr_fillBufferAligned, which measures
//      6.5 TB/s on this very buffer => ~42 us.
//   B) scatter_kernel: write only even output rows' payload: one f4
//      {x,0,y,0} per input f2. 67 MB read + 134 MB full-line writes
//      => ~33 us at m13 copy BW (6.3 TB/s).
// Single-pass versions (one-shot, wave-loop, nt/no-nt) all floor at
// 135-145 us = 2.4 TB/s effective; each half here has a measured
// same-chip analog running at ~6.4 TB/s.

typedef float f2 __attribute__((ext_vector_type(2)));
typedef float f4 __attribute__((ext_vector_type(4)));

__global__ __launch_bounds__(256) void zero_kernel(float* __restrict__ out) {
    unsigned v = blockIdx.x * blockDim.x + threadIdx.x;
    ((f4*)out)[v] = (f4){0.f, 0.f, 0.f, 0.f};
}

__global__ __launch_bounds__(256) void scatter_kernel(
    const float* __restrict__ in, float* __restrict__ out) {
    unsigned v = blockIdx.x * blockDim.x + threadIdx.x;  // input f2 index
    unsigned t = v & 63u;   // f2 index within input row (64 per 128-f row)
    unsigned p = v >> 6;    // input row = output row-pair, 0..131071
    f2 x = ((const f2*)in)[v];
    // even output row of pair p starts at float offset p*512;
    // input cols (2t,2t+1) -> output cols (4t, 4t+2): one aligned f4.
    f4* dst = (f4*)(out + (size_t)p * 512 + (size_t)t * 4);
    *dst = (f4){x.x, 0.f, x.y, 0.f};
}

extern "C" void kernel_launch(void* const* d_in, const int* in_sizes, int n_in,
                              void* d_out, int out_size, void* d_ws, size_t ws_size,
                              hipStream_t stream) {
    const float* feats = (const float*)d_in[0];
    float* out = (float*)d_out;
    // A: out_size/4 = 16,777,216 f4 stores -> 65536 blocks of 256
    unsigned n_vec4 = (unsigned)(out_size / 4);
    zero_kernel<<<dim3(n_vec4 / 256), dim3(256), 0, stream>>>(out);
    // B: 16*64*128*128/2 = 8,388,608 input f2 -> 32768 blocks of 256
    unsigned n_f2 = 8388608u;
    scatter_kernel<<<dim3(n_f2 / 256), dim3(256), 0, stream>>>(feats, out);
}